// Round 5
// baseline (356.715 us; speedup 1.0000x reference)
//
#include <hip/hip_runtime.h>
#include <math.h>

#define BATCH 4
#define SEQ 2048
#define FEAT 512
#define NHEADS 8
#define HD 64
#define NROWS (BATCH*SEQ)   // 8192

typedef __attribute__((ext_vector_type(4)))  float f32x4;
typedef __attribute__((ext_vector_type(16))) float f32x16;
typedef __attribute__((ext_vector_type(8)))  short s16x8;
typedef __attribute__((ext_vector_type(8)))  unsigned short u16x8;
typedef __attribute__((ext_vector_type(4)))  unsigned int u32x4;

static __device__ __forceinline__ unsigned short f2bf(float x) {
  unsigned int u = __builtin_bit_cast(unsigned int, x);
  unsigned int r = (u + 0x7FFFu + ((u >> 16) & 1u)) >> 16;
  return (unsigned short)r;
}
static __device__ __forceinline__ float bf2f(unsigned short h) {
  unsigned int u = ((unsigned int)h) << 16;
  return __builtin_bit_cast(float, u);
}
static __device__ __forceinline__ void split2(float x, unsigned short& h, unsigned short& l) {
  h = f2bf(x);
  l = f2bf(x - bf2f(h));
}

// ---------------------------------------------------------------------------
// Fused QKV projection. z=0: Q (scale 1/8) -> (B,H,T,Hd) hi/lo
//                       z=1: K            -> (B,H,T,Hd) hi/lo
//                       z=2: V            -> (B,H,Hd,T) hi/lo (LDS transpose)
// ---------------------------------------------------------------------------
__global__ __launch_bounds__(256) void qkv_proj(
    const float* __restrict__ xc, const float* __restrict__ xp,
    const float* __restrict__ wq, const float* __restrict__ bq,
    const float* __restrict__ wk, const float* __restrict__ bk,
    const float* __restrict__ wv, const float* __restrict__ bv,
    unsigned short* __restrict__ Qhi, unsigned short* __restrict__ Qlo,
    unsigned short* __restrict__ Khi, unsigned short* __restrict__ Klo,
    unsigned short* __restrict__ Vthi, unsigned short* __restrict__ Vtlo)
{
  __shared__ unsigned short Xhi[128 * 64], Xlo[128 * 64];
  __shared__ unsigned short Whi[64 * 64],  Wlo[64 * 64];

  const int z = blockIdx.z;
  const float* X  = (z == 0) ? xc : xp;
  const float* W  = (z == 0) ? wq : (z == 1) ? wk : wv;
  const float* Bp = (z == 0) ? bq : (z == 1) ? bk : bv;
  unsigned short* Ohi = (z == 0) ? Qhi : (z == 1) ? Khi : Vthi;
  unsigned short* Olo = (z == 0) ? Qlo : (z == 1) ? Klo : Vtlo;
  const float scale = (z == 0) ? 0.125f : 1.0f;

  const int tid  = threadIdx.x;
  const int lane = tid & 63;
  const int wave = tid >> 6;
  const int g = lane >> 4, j = lane & 15;
  const int wm = (wave >> 1) * 64;
  const int wn = (wave & 1) * 32;
  const int row0 = blockIdx.x * 128;
  const int col0 = blockIdx.y * 64;

  f32x4 acc[4][2];
#pragma unroll
  for (int mi = 0; mi < 4; ++mi)
#pragma unroll
    for (int ni = 0; ni < 2; ++ni) acc[mi][ni] = (f32x4)0.f;

  const int srow = tid >> 4;        // 0..15
  const int sk   = (tid & 15) * 4;  // 0..60

  for (int kt = 0; kt < FEAT; kt += 64) {
    f32x4 xr[8], wr[4];
#pragma unroll
    for (int p = 0; p < 8; ++p)
      xr[p] = *reinterpret_cast<const f32x4*>(&X[(size_t)(row0 + srow + p * 16) * FEAT + kt + sk]);
#pragma unroll
    for (int p = 0; p < 4; ++p)
      wr[p] = *reinterpret_cast<const f32x4*>(&W[(size_t)(col0 + srow + p * 16) * FEAT + kt + sk]);
    __syncthreads();
#pragma unroll
    for (int p = 0; p < 8; ++p) {
      const int r = srow + p * 16;
      const int el = r * 64 + (sk ^ ((r & 7) << 3));
#pragma unroll
      for (int i = 0; i < 4; ++i) { unsigned short hh, ll; split2(xr[p][i], hh, ll); Xhi[el + i] = hh; Xlo[el + i] = ll; }
    }
#pragma unroll
    for (int p = 0; p < 4; ++p) {
      const int r = srow + p * 16;
      const int el = r * 64 + (sk ^ ((r & 7) << 3));
#pragma unroll
      for (int i = 0; i < 4; ++i) { unsigned short hh, ll; split2(wr[p][i], hh, ll); Whi[el + i] = hh; Wlo[el + i] = ll; }
    }
    __syncthreads();

#pragma unroll
    for (int c = 0; c < 2; ++c) {
      const int koff = c * 32 + g * 8;
      s16x8 ah[4], al[4], bh[2], bl[2];
#pragma unroll
      for (int mi = 0; mi < 4; ++mi) {
        const int r = wm + mi * 16 + j;
        const int el = r * 64 + (koff ^ ((r & 7) << 3));
        ah[mi] = *reinterpret_cast<const s16x8*>(&Xhi[el]);
        al[mi] = *reinterpret_cast<const s16x8*>(&Xlo[el]);
      }
#pragma unroll
      for (int ni = 0; ni < 2; ++ni) {
        const int r = wn + ni * 16 + j;
        const int el = r * 64 + (koff ^ ((r & 7) << 3));
        bh[ni] = *reinterpret_cast<const s16x8*>(&Whi[el]);
        bl[ni] = *reinterpret_cast<const s16x8*>(&Wlo[el]);
      }
#pragma unroll
      for (int mi = 0; mi < 4; ++mi)
#pragma unroll
        for (int ni = 0; ni < 2; ++ni) {
          acc[mi][ni] = __builtin_amdgcn_mfma_f32_16x16x32_bf16(ah[mi], bh[ni], acc[mi][ni], 0, 0, 0);
          acc[mi][ni] = __builtin_amdgcn_mfma_f32_16x16x32_bf16(ah[mi], bl[ni], acc[mi][ni], 0, 0, 0);
          acc[mi][ni] = __builtin_amdgcn_mfma_f32_16x16x32_bf16(al[mi], bh[ni], acc[mi][ni], 0, 0, 0);
        }
    }
  }

  if (z < 2) {
#pragma unroll
    for (int ni = 0; ni < 2; ++ni) {
      const int colc = col0 + wn + ni * 16 + j;
      const float bj = Bp[colc];
      const int h = colc >> 6, hd = colc & 63;
#pragma unroll
      for (int mi = 0; mi < 4; ++mi)
#pragma unroll
        for (int r = 0; r < 4; ++r) {
          const int rowc = row0 + wm + mi * 16 + (g << 2) + r;
          const int b = rowc >> 11, t = rowc & 2047;
          const float v = (acc[mi][ni][r] + bj) * scale;
          unsigned short hh, ll; split2(v, hh, ll);
          const size_t off = (((size_t)b * NHEADS + h) * SEQ + t) * HD + hd;
          Ohi[off] = hh; Olo[off] = ll;
        }
    }
  } else {
    // V: transpose via LDS -> (B,H,Hd,T)
    __syncthreads();
#pragma unroll
    for (int ni = 0; ni < 2; ++ni) {
      const int hdl = wn + ni * 16 + j;
      const float bj = Bp[col0 + hdl];
#pragma unroll
      for (int mi = 0; mi < 4; ++mi)
#pragma unroll
        for (int r = 0; r < 4; ++r) {
          const int lt = wm + mi * 16 + (g << 2) + r;
          const float v = acc[mi][ni][r] + bj;
          unsigned short hh, ll; split2(v, hh, ll);
          const int el = lt * 64 + (hdl ^ ((lt & 7) << 3));
          Xhi[el] = hh; Xlo[el] = ll;
        }
    }
    __syncthreads();
    const int b = row0 >> 11, h = col0 >> 6;
    const int tbase = row0 & 2047;
#pragma unroll
    for (int c = 0; c < 4; ++c) {
      const int chunk = c * 256 + tid;
      const int hd = chunk >> 4;
      const int t0 = (chunk & 15) * 8;
      u16x8 vh, vl;
#pragma unroll
      for (int i = 0; i < 8; ++i) {
        const int lt = t0 + i;
        const int el = lt * 64 + (hd ^ ((lt & 7) << 3));
        vh[i] = Xhi[el]; vl[i] = Xlo[el];
      }
      const size_t off = (((size_t)b * NHEADS + h) * HD + hd) * SEQ + tbase + t0;
      *reinterpret_cast<u16x8*>(&Vthi[off]) = vh;
      *reinterpret_cast<u16x8*>(&Vtlo[off]) = vl;
    }
  }
}

// ---------------------------------------------------------------------------
// Output projection: out[r,j] = sum_k AO[r,k]*wo[j,k] + bo[j]
// ---------------------------------------------------------------------------
__global__ __launch_bounds__(256) void out_proj(
    const float* __restrict__ X, const float* __restrict__ W,
    const float* __restrict__ bias, float* __restrict__ out)
{
  __shared__ unsigned short Xhi[128 * 64], Xlo[128 * 64];
  __shared__ unsigned short Whi[64 * 64],  Wlo[64 * 64];

  const int tid  = threadIdx.x;
  const int lane = tid & 63;
  const int wave = tid >> 6;
  const int g = lane >> 4, j = lane & 15;
  const int wm = (wave >> 1) * 64;
  const int wn = (wave & 1) * 32;
  const int row0 = blockIdx.x * 128;
  const int col0 = blockIdx.y * 64;

  f32x4 acc[4][2];
#pragma unroll
  for (int mi = 0; mi < 4; ++mi)
#pragma unroll
    for (int ni = 0; ni < 2; ++ni) acc[mi][ni] = (f32x4)0.f;

  const int srow = tid >> 4;
  const int sk   = (tid & 15) * 4;

  for (int kt = 0; kt < FEAT; kt += 64) {
    f32x4 xr[8], wr[4];
#pragma unroll
    for (int p = 0; p < 8; ++p)
      xr[p] = *reinterpret_cast<const f32x4*>(&X[(size_t)(row0 + srow + p * 16) * FEAT + kt + sk]);
#pragma unroll
    for (int p = 0; p < 4; ++p)
      wr[p] = *reinterpret_cast<const f32x4*>(&W[(size_t)(col0 + srow + p * 16) * FEAT + kt + sk]);
    __syncthreads();
#pragma unroll
    for (int p = 0; p < 8; ++p) {
      const int r = srow + p * 16;
      const int el = r * 64 + (sk ^ ((r & 7) << 3));
#pragma unroll
      for (int i = 0; i < 4; ++i) { unsigned short hh, ll; split2(xr[p][i], hh, ll); Xhi[el + i] = hh; Xlo[el + i] = ll; }
    }
#pragma unroll
    for (int p = 0; p < 4; ++p) {
      const int r = srow + p * 16;
      const int el = r * 64 + (sk ^ ((r & 7) << 3));
#pragma unroll
      for (int i = 0; i < 4; ++i) { unsigned short hh, ll; split2(wr[p][i], hh, ll); Whi[el + i] = hh; Wlo[el + i] = ll; }
    }
    __syncthreads();

#pragma unroll
    for (int c = 0; c < 2; ++c) {
      const int koff = c * 32 + g * 8;
      s16x8 ah[4], al[4], bh[2], bl[2];
#pragma unroll
      for (int mi = 0; mi < 4; ++mi) {
        const int r = wm + mi * 16 + j;
        const int el = r * 64 + (koff ^ ((r & 7) << 3));
        ah[mi] = *reinterpret_cast<const s16x8*>(&Xhi[el]);
        al[mi] = *reinterpret_cast<const s16x8*>(&Xlo[el]);
      }
#pragma unroll
      for (int ni = 0; ni < 2; ++ni) {
        const int r = wn + ni * 16 + j;
        const int el = r * 64 + (koff ^ ((r & 7) << 3));
        bh[ni] = *reinterpret_cast<const s16x8*>(&Whi[el]);
        bl[ni] = *reinterpret_cast<const s16x8*>(&Wlo[el]);
      }
#pragma unroll
      for (int mi = 0; mi < 4; ++mi)
#pragma unroll
        for (int ni = 0; ni < 2; ++ni) {
          acc[mi][ni] = __builtin_amdgcn_mfma_f32_16x16x32_bf16(ah[mi], bh[ni], acc[mi][ni], 0, 0, 0);
          acc[mi][ni] = __builtin_amdgcn_mfma_f32_16x16x32_bf16(ah[mi], bl[ni], acc[mi][ni], 0, 0, 0);
          acc[mi][ni] = __builtin_amdgcn_mfma_f32_16x16x32_bf16(al[mi], bh[ni], acc[mi][ni], 0, 0, 0);
        }
    }
  }

#pragma unroll
  for (int ni = 0; ni < 2; ++ni) {
    const int colc = col0 + wn + ni * 16 + j;
    const float bj = bias[colc];
#pragma unroll
    for (int mi = 0; mi < 4; ++mi)
#pragma unroll
      for (int r = 0; r < 4; ++r) {
        const int rowc = row0 + wm + mi * 16 + (g << 2) + r;
        out[(size_t)rowc * FEAT + colc] = acc[mi][ni][r] + bj;
      }
  }
}

// ---------------------------------------------------------------------------
// Flash attention, swapped-operand 32x32x16 MFMA, direct-global K/V, no
// k-loop barriers. Block = 4 waves x 32 q-rows = 128 q. Grid 512 (swizzled).
// S^T = K*Q^T puts q at lane&31. All cross-half exchanges use __shfl_xor
// (known semantics); P hi/lo via proven split2.
// ---------------------------------------------------------------------------
__global__ __launch_bounds__(256, 2) void attn_mfma32(
    const unsigned short* __restrict__ Qhi, const unsigned short* __restrict__ Qlo,
    const unsigned short* __restrict__ Khi, const unsigned short* __restrict__ Klo,
    const unsigned short* __restrict__ Vthi, const unsigned short* __restrict__ Vtlo,
    float* __restrict__ AO)
{
  __shared__ float bcast[4][32];

  const int tid = threadIdx.x, lane = tid & 63, wave = tid >> 6;
  const int hfl = lane >> 5;      // half of wave
  const int l31 = lane & 31;

  // XCD-chunked swizzle: 512 blocks = 8 XCDs x 64; each XCD gets 4 bh (4MB KV)
  const int bid = blockIdx.x;
  const int swz = (bid & 7) * 64 + (bid >> 3);
  const int qt  = swz & 15;
  const int bh  = swz >> 4;
  const int b = bh >> 3, h = bh & 7;

  const int q0 = qt * 128 + wave * 32;
  const size_t kvbase = (size_t)bh * SEQ * HD;

  // Q B-fragments (col=q=lane&31, k=hd=c*16+hfl*8+i), pre-scaled by 1/8
  s16x8 qh[4], ql[4];
  {
    const size_t qoff = kvbase + (size_t)(q0 + l31) * HD + hfl * 8;
#pragma unroll
    for (int c = 0; c < 4; ++c) {
      qh[c] = *reinterpret_cast<const s16x8*>(&Qhi[qoff + c * 16]);
      ql[c] = *reinterpret_cast<const s16x8*>(&Qlo[qoff + c * 16]);
    }
  }

  f32x16 oacc0 = (f32x16)0.f, oacc1 = (f32x16)0.f;
  float m = -INFINITY, l = 0.f;

  const unsigned short* kh_p = &Khi[kvbase + (size_t)l31 * HD + hfl * 8];
  const unsigned short* kl_p = &Klo[kvbase + (size_t)l31 * HD + hfl * 8];
  const size_t v0off = ((size_t)bh * HD + l31) * SEQ + hfl * 8;        // hd-tile 0
  const size_t v1off = ((size_t)bh * HD + 32 + l31) * SEQ + hfl * 8;   // hd-tile 1

  for (int kt = 0; kt < SEQ; kt += 32) {
    // ---- S^T = K Q^T : A-frag row=key=lane&31, k=hd ----
    f32x16 st = (f32x16)0.f;
    const unsigned short* kh_t = kh_p + (size_t)kt * HD;
    const unsigned short* kl_t = kl_p + (size_t)kt * HD;
#pragma unroll
    for (int c = 0; c < 4; ++c) {
      const s16x8 ah = *reinterpret_cast<const s16x8*>(&kh_t[c * 16]);
      const s16x8 al = *reinterpret_cast<const s16x8*>(&kl_t[c * 16]);
      st = __builtin_amdgcn_mfma_f32_32x32x16_bf16(ah, qh[c], st, 0, 0, 0);
      st = __builtin_amdgcn_mfma_f32_32x32x16_bf16(ah, ql[c], st, 0, 0, 0);
      st = __builtin_amdgcn_mfma_f32_32x32x16_bf16(al, qh[c], st, 0, 0, 0);
    }

    // ---- tile max over this lane's 16 keys + cross-half combine ----
    float pm = fmaxf(
        fmaxf(fmaxf(fmaxf(st[0], st[1]), fmaxf(st[2], st[3])),
              fmaxf(fmaxf(st[4], st[5]), fmaxf(st[6], st[7]))),
        fmaxf(fmaxf(fmaxf(st[8], st[9]), fmaxf(st[10], st[11])),
              fmaxf(fmaxf(st[12], st[13]), fmaxf(st[14], st[15]))));
    pm = fmaxf(pm, __shfl_xor(pm, 32));   // full 32-key row max, both halves

    // ---- defer-max rescale (rare; tile 0 always, corr=0 there) ----
    if (__any(pm > m + 8.f)) {
      const float mnew = fmaxf(m, pm);
      const float corr = __expf(m - mnew);
      m = mnew; l *= corr;
      if (lane < 32) bcast[wave][l31] = corr;
      f32x4 c4[4];
#pragma unroll
      for (int rq = 0; rq < 4; ++rq)
        c4[rq] = *reinterpret_cast<const f32x4*>(&bcast[wave][rq * 8 + hfl * 4]);
#pragma unroll
      for (int r = 0; r < 16; ++r) {
        const float cc = c4[r >> 2][r & 3];
        oacc0[r] *= cc; oacc1[r] *= cc;
      }
    }

    // ---- p = exp(s - m), row sum ----
    float rs = 0.f;
#pragma unroll
    for (int r = 0; r < 16; ++r) { st[r] = __expf(st[r] - m); rs += st[r]; }
    rs += __shfl_xor(rs, 32);
    l += rs;

    // ---- pack P hi/lo (proven split2), exchange halves via shfl_xor ----
    // lane (l31,hfl) holds keys crow(r,hfl)=(r&3)+8*(r>>2)+4*hfl; word p =
    // keys(2p',2p'+1) pattern: hfl0 words: (0,1)(2,3)(8,9)(10,11)(16,17)...
    // A-frag needs contiguous keys: word j of frag0 = {keys(2j)@hfl0, keys(8+2j)@hfl1}
    unsigned int wh[8], wl[8];
#pragma unroll
    for (int p = 0; p < 8; ++p) {
      unsigned short h0, l0, h1, l1;
      split2(st[2 * p], h0, l0);
      split2(st[2 * p + 1], h1, l1);
      wh[p] = (unsigned int)h0 | ((unsigned int)h1 << 16);
      wl[p] = (unsigned int)l0 | ((unsigned int)l1 << 16);
    }
    unsigned int sh[8], sl[8];
#pragma unroll
    for (int p = 0; p < 8; ++p) {
      sh[p] = (unsigned int)__shfl_xor((int)wh[p], 32);
      sl[p] = (unsigned int)__shfl_xor((int)wl[p], 32);
    }
    const bool lo = (hfl == 0);
    const unsigned int ah0 = lo ? wh[0] : sh[2];
    const unsigned int ah1 = lo ? wh[1] : sh[3];
    const unsigned int ah2 = lo ? sh[0] : wh[2];
    const unsigned int ah3 = lo ? sh[1] : wh[3];
    const unsigned int ah4 = lo ? wh[4] : sh[6];
    const unsigned int ah5 = lo ? wh[5] : sh[7];
    const unsigned int ah6 = lo ? sh[4] : wh[6];
    const unsigned int ah7 = lo ? sh[5] : wh[7];
    const unsigned int al0 = lo ? wl[0] : sl[2];
    const unsigned int al1 = lo ? wl[1] : sl[3];
    const unsigned int al2 = lo ? sl[0] : wl[2];
    const unsigned int al3 = lo ? sl[1] : wl[3];
    const unsigned int al4 = lo ? wl[4] : sl[6];
    const unsigned int al5 = lo ? wl[5] : sl[7];
    const unsigned int al6 = lo ? sl[4] : wl[6];
    const unsigned int al7 = lo ? sl[5] : wl[7];
    const s16x8 pa0h = __builtin_bit_cast(s16x8, (u32x4){ah0, ah1, ah2, ah3});
    const s16x8 pa1h = __builtin_bit_cast(s16x8, (u32x4){ah4, ah5, ah6, ah7});
    const s16x8 pa0l = __builtin_bit_cast(s16x8, (u32x4){al0, al1, al2, al3});
    const s16x8 pa1l = __builtin_bit_cast(s16x8, (u32x4){al4, al5, al6, al7});

    // ---- O += P V : B-frag col=hd=lane&31(+32), k=key from Vt(B,H,Hd,T) ----
    {
      const s16x8 vh00 = *reinterpret_cast<const s16x8*>(&Vthi[v0off + kt]);
      const s16x8 vl00 = *reinterpret_cast<const s16x8*>(&Vtlo[v0off + kt]);
      const s16x8 vh01 = *reinterpret_cast<const s16x8*>(&Vthi[v0off + kt + 16]);
      const s16x8 vl01 = *reinterpret_cast<const s16x8*>(&Vtlo[v0off + kt + 16]);
      oacc0 = __builtin_amdgcn_mfma_f32_32x32x16_bf16(pa0h, vh00, oacc0, 0, 0, 0);
      oacc0 = __builtin_amdgcn_mfma_f32_32x32x16_bf16(pa0h, vl00, oacc0, 0, 0, 0);
      oacc0 = __builtin_amdgcn_mfma_f32_32x32x16_bf16(pa0l, vh00, oacc0, 0, 0, 0);
      oacc0 = __builtin_amdgcn_mfma_f32_32x32x16_bf16(pa1h, vh01, oacc0, 0, 0, 0);
      oacc0 = __builtin_amdgcn_mfma_f32_32x32x16_bf16(pa1h, vl01, oacc0, 0, 0, 0);
      oacc0 = __builtin_amdgcn_mfma_f32_32x32x16_bf16(pa1l, vh01, oacc0, 0, 0, 0);
      const s16x8 vh10 = *reinterpret_cast<const s16x8*>(&Vthi[v1off + kt]);
      const s16x8 vl10 = *reinterpret_cast<const s16x8*>(&Vtlo[v1off + kt]);
      const s16x8 vh11 = *reinterpret_cast<const s16x8*>(&Vthi[v1off + kt + 16]);
      const s16x8 vl11 = *reinterpret_cast<const s16x8*>(&Vtlo[v1off + kt + 16]);
      oacc1 = __builtin_amdgcn_mfma_f32_32x32x16_bf16(pa0h, vh10, oacc1, 0, 0, 0);
      oacc1 = __builtin_amdgcn_mfma_f32_32x32x16_bf16(pa0h, vl10, oacc1, 0, 0, 0);
      oacc1 = __builtin_amdgcn_mfma_f32_32x32x16_bf16(pa0l, vh10, oacc1, 0, 0, 0);
      oacc1 = __builtin_amdgcn_mfma_f32_32x32x16_bf16(pa1h, vh11, oacc1, 0, 0, 0);
      oacc1 = __builtin_amdgcn_mfma_f32_32x32x16_bf16(pa1h, vl11, oacc1, 0, 0, 0);
      oacc1 = __builtin_amdgcn_mfma_f32_32x32x16_bf16(pa1l, vh11, oacc1, 0, 0, 0);
    }
  }

  // ---- normalize (1/l broadcast via per-wave LDS) and store ----
  if (lane < 32) bcast[wave][l31] = 1.f / l;
  f32x4 i4[4];
#pragma unroll
  for (int rq = 0; rq < 4; ++rq)
    i4[rq] = *reinterpret_cast<const f32x4*>(&bcast[wave][rq * 8 + hfl * 4]);

#pragma unroll
  for (int r = 0; r < 16; ++r) {
    const int q = q0 + (r & 3) + 8 * (r >> 2) + 4 * hfl;
    const float inv = i4[r >> 2][r & 3];
    float* dst = &AO[((size_t)b * SEQ + q) * FEAT + h * HD + l31];
    dst[0]  = oacc0[r] * inv;
    dst[32] = oacc1[r] * inv;
  }
}

extern "C" void kernel_launch(void* const* d_in, const int* in_sizes, int n_in,
                              void* d_out, int out_size, void* d_ws, size_t ws_size,
                              hipStream_t stream) {
  const float* x_cur  = (const float*)d_in[0];
  const float* x_past = (const float*)d_in[1];
  const float* wq = (const float*)d_in[2];
  const float* bq = (const float*)d_in[3];
  const float* wk = (const float*)d_in[4];
  const float* bk = (const float*)d_in[5];
  const float* wv = (const float*)d_in[6];
  const float* bv = (const float*)d_in[7];
  const float* wo = (const float*)d_in[8];
  const float* bo = (const float*)d_in[9];
  float* out = (float*)d_out;

  const size_t n = (size_t)NROWS * FEAT;
  unsigned short* Qhi  = (unsigned short*)d_ws;
  unsigned short* Qlo  = Qhi + n;
  unsigned short* Khi  = Qhi + 2 * n;
  unsigned short* Klo  = Qhi + 3 * n;
  unsigned short* Vthi = Qhi + 4 * n;
  unsigned short* Vtlo = Qhi + 5 * n;
  float* AO = (float*)(Qhi + 6 * n);

  dim3 block(256);
  dim3 gqkv(NROWS / 128, FEAT / 64, 3);
  qkv_proj<<<gqkv, block, 0, stream>>>(x_cur, x_past, wq, bq, wk, bk, wv, bv,
                                       Qhi, Qlo, Khi, Klo, Vthi, Vtlo);

  attn_mfma32<<<dim3(512), block, 0, stream>>>(Qhi, Qlo, Khi, Klo, Vthi, Vtlo, AO);

  dim3 gout(NROWS / 128, FEAT / 64);
  out_proj<<<gout, block, 0, stream>>>(AO, wo, bo, out);
}

// Round 6
// 326.772 us; speedup vs baseline: 1.0916x; 1.0916x over previous
//
#include <hip/hip_runtime.h>
#include <math.h>

#define BATCH 4
#define SEQ 2048
#define FEAT 512
#define NHEADS 8
#define HD 64
#define NROWS (BATCH*SEQ)   // 8192

typedef __attribute__((ext_vector_type(4)))  float f32x4;
typedef __attribute__((ext_vector_type(16))) float f32x16;
typedef __attribute__((ext_vector_type(8)))  short s16x8;
typedef __attribute__((ext_vector_type(8)))  unsigned short u16x8;
typedef __attribute__((ext_vector_type(4)))  unsigned int u32x4;

static __device__ __forceinline__ unsigned short f2bf(float x) {
  unsigned int u = __builtin_bit_cast(unsigned int, x);
  unsigned int r = (u + 0x7FFFu + ((u >> 16) & 1u)) >> 16;
  return (unsigned short)r;
}
static __device__ __forceinline__ float bf2f(unsigned short h) {
  unsigned int u = ((unsigned int)h) << 16;
  return __builtin_bit_cast(float, u);
}
static __device__ __forceinline__ void split2(float x, unsigned short& h, unsigned short& l) {
  h = f2bf(x);
  l = f2bf(x - bf2f(h));
}

// ---------------------------------------------------------------------------
// Fused QKV projection. z=0: Q (scale 1/8) -> (B,H,T,Hd) hi/lo
//                       z=1: K            -> (B,H,T,Hd) hi/lo
//                       z=2: V            -> (B,H,Hd,T) hi/lo (LDS transpose)
// ---------------------------------------------------------------------------
__global__ __launch_bounds__(256) void qkv_proj(
    const float* __restrict__ xc, const float* __restrict__ xp,
    const float* __restrict__ wq, const float* __restrict__ bq,
    const float* __restrict__ wk, const float* __restrict__ bk,
    const float* __restrict__ wv, const float* __restrict__ bv,
    unsigned short* __restrict__ Qhi, unsigned short* __restrict__ Qlo,
    unsigned short* __restrict__ Khi, unsigned short* __restrict__ Klo,
    unsigned short* __restrict__ Vthi, unsigned short* __restrict__ Vtlo)
{
  __shared__ unsigned short Xhi[128 * 64], Xlo[128 * 64];
  __shared__ unsigned short Whi[64 * 64],  Wlo[64 * 64];

  const int z = blockIdx.z;
  const float* X  = (z == 0) ? xc : xp;
  const float* W  = (z == 0) ? wq : (z == 1) ? wk : wv;
  const float* Bp = (z == 0) ? bq : (z == 1) ? bk : bv;
  unsigned short* Ohi = (z == 0) ? Qhi : (z == 1) ? Khi : Vthi;
  unsigned short* Olo = (z == 0) ? Qlo : (z == 1) ? Klo : Vtlo;
  const float scale = (z == 0) ? 0.125f : 1.0f;

  const int tid  = threadIdx.x;
  const int lane = tid & 63;
  const int wave = tid >> 6;
  const int g = lane >> 4, j = lane & 15;
  const int wm = (wave >> 1) * 64;
  const int wn = (wave & 1) * 32;
  const int row0 = blockIdx.x * 128;
  const int col0 = blockIdx.y * 64;

  f32x4 acc[4][2];
#pragma unroll
  for (int mi = 0; mi < 4; ++mi)
#pragma unroll
    for (int ni = 0; ni < 2; ++ni) acc[mi][ni] = (f32x4)0.f;

  const int srow = tid >> 4;        // 0..15
  const int sk   = (tid & 15) * 4;  // 0..60

  for (int kt = 0; kt < FEAT; kt += 64) {
    f32x4 xr[8], wr[4];
#pragma unroll
    for (int p = 0; p < 8; ++p)
      xr[p] = *reinterpret_cast<const f32x4*>(&X[(size_t)(row0 + srow + p * 16) * FEAT + kt + sk]);
#pragma unroll
    for (int p = 0; p < 4; ++p)
      wr[p] = *reinterpret_cast<const f32x4*>(&W[(size_t)(col0 + srow + p * 16) * FEAT + kt + sk]);
    __syncthreads();
#pragma unroll
    for (int p = 0; p < 8; ++p) {
      const int r = srow + p * 16;
      const int el = r * 64 + (sk ^ ((r & 7) << 3));
#pragma unroll
      for (int i = 0; i < 4; ++i) { unsigned short hh, ll; split2(xr[p][i], hh, ll); Xhi[el + i] = hh; Xlo[el + i] = ll; }
    }
#pragma unroll
    for (int p = 0; p < 4; ++p) {
      const int r = srow + p * 16;
      const int el = r * 64 + (sk ^ ((r & 7) << 3));
#pragma unroll
      for (int i = 0; i < 4; ++i) { unsigned short hh, ll; split2(wr[p][i], hh, ll); Whi[el + i] = hh; Wlo[el + i] = ll; }
    }
    __syncthreads();

#pragma unroll
    for (int c = 0; c < 2; ++c) {
      const int koff = c * 32 + g * 8;
      s16x8 ah[4], al[4], bh[2], bl[2];
#pragma unroll
      for (int mi = 0; mi < 4; ++mi) {
        const int r = wm + mi * 16 + j;
        const int el = r * 64 + (koff ^ ((r & 7) << 3));
        ah[mi] = *reinterpret_cast<const s16x8*>(&Xhi[el]);
        al[mi] = *reinterpret_cast<const s16x8*>(&Xlo[el]);
      }
#pragma unroll
      for (int ni = 0; ni < 2; ++ni) {
        const int r = wn + ni * 16 + j;
        const int el = r * 64 + (koff ^ ((r & 7) << 3));
        bh[ni] = *reinterpret_cast<const s16x8*>(&Whi[el]);
        bl[ni] = *reinterpret_cast<const s16x8*>(&Wlo[el]);
      }
#pragma unroll
      for (int mi = 0; mi < 4; ++mi)
#pragma unroll
        for (int ni = 0; ni < 2; ++ni) {
          acc[mi][ni] = __builtin_amdgcn_mfma_f32_16x16x32_bf16(ah[mi], bh[ni], acc[mi][ni], 0, 0, 0);
          acc[mi][ni] = __builtin_amdgcn_mfma_f32_16x16x32_bf16(ah[mi], bl[ni], acc[mi][ni], 0, 0, 0);
          acc[mi][ni] = __builtin_amdgcn_mfma_f32_16x16x32_bf16(al[mi], bh[ni], acc[mi][ni], 0, 0, 0);
        }
    }
  }

  if (z < 2) {
#pragma unroll
    for (int ni = 0; ni < 2; ++ni) {
      const int colc = col0 + wn + ni * 16 + j;
      const float bj = Bp[colc];
      const int h = colc >> 6, hd = colc & 63;
#pragma unroll
      for (int mi = 0; mi < 4; ++mi)
#pragma unroll
        for (int r = 0; r < 4; ++r) {
          const int rowc = row0 + wm + mi * 16 + (g << 2) + r;
          const int b = rowc >> 11, t = rowc & 2047;
          const float v = (acc[mi][ni][r] + bj) * scale;
          unsigned short hh, ll; split2(v, hh, ll);
          const size_t off = (((size_t)b * NHEADS + h) * SEQ + t) * HD + hd;
          Ohi[off] = hh; Olo[off] = ll;
        }
    }
  } else {
    // V: transpose via LDS -> (B,H,Hd,T)
    __syncthreads();
#pragma unroll
    for (int ni = 0; ni < 2; ++ni) {
      const int hdl = wn + ni * 16 + j;
      const float bj = Bp[col0 + hdl];
#pragma unroll
      for (int mi = 0; mi < 4; ++mi)
#pragma unroll
        for (int r = 0; r < 4; ++r) {
          const int lt = wm + mi * 16 + (g << 2) + r;
          const float v = acc[mi][ni][r] + bj;
          unsigned short hh, ll; split2(v, hh, ll);
          const int el = lt * 64 + (hdl ^ ((lt & 7) << 3));
          Xhi[el] = hh; Xlo[el] = ll;
        }
    }
    __syncthreads();
    const int b = row0 >> 11, h = col0 >> 6;
    const int tbase = row0 & 2047;
#pragma unroll
    for (int c = 0; c < 4; ++c) {
      const int chunk = c * 256 + tid;
      const int hd = chunk >> 4;
      const int t0 = (chunk & 15) * 8;
      u16x8 vh, vl;
#pragma unroll
      for (int i = 0; i < 8; ++i) {
        const int lt = t0 + i;
        const int el = lt * 64 + (hd ^ ((lt & 7) << 3));
        vh[i] = Xhi[el]; vl[i] = Xlo[el];
      }
      const size_t off = (((size_t)b * NHEADS + h) * HD + hd) * SEQ + tbase + t0;
      *reinterpret_cast<u16x8*>(&Vthi[off]) = vh;
      *reinterpret_cast<u16x8*>(&Vtlo[off]) = vl;
    }
  }
}

// ---------------------------------------------------------------------------
// Output projection: out[r,j] = sum_k AO[r,k]*wo[j,k] + bo[j]
// ---------------------------------------------------------------------------
__global__ __launch_bounds__(256) void out_proj(
    const float* __restrict__ X, const float* __restrict__ W,
    const float* __restrict__ bias, float* __restrict__ out)
{
  __shared__ unsigned short Xhi[128 * 64], Xlo[128 * 64];
  __shared__ unsigned short Whi[64 * 64],  Wlo[64 * 64];

  const int tid  = threadIdx.x;
  const int lane = tid & 63;
  const int wave = tid >> 6;
  const int g = lane >> 4, j = lane & 15;
  const int wm = (wave >> 1) * 64;
  const int wn = (wave & 1) * 32;
  const int row0 = blockIdx.x * 128;
  const int col0 = blockIdx.y * 64;

  f32x4 acc[4][2];
#pragma unroll
  for (int mi = 0; mi < 4; ++mi)
#pragma unroll
    for (int ni = 0; ni < 2; ++ni) acc[mi][ni] = (f32x4)0.f;

  const int srow = tid >> 4;
  const int sk   = (tid & 15) * 4;

  for (int kt = 0; kt < FEAT; kt += 64) {
    f32x4 xr[8], wr[4];
#pragma unroll
    for (int p = 0; p < 8; ++p)
      xr[p] = *reinterpret_cast<const f32x4*>(&X[(size_t)(row0 + srow + p * 16) * FEAT + kt + sk]);
#pragma unroll
    for (int p = 0; p < 4; ++p)
      wr[p] = *reinterpret_cast<const f32x4*>(&W[(size_t)(col0 + srow + p * 16) * FEAT + kt + sk]);
    __syncthreads();
#pragma unroll
    for (int p = 0; p < 8; ++p) {
      const int r = srow + p * 16;
      const int el = r * 64 + (sk ^ ((r & 7) << 3));
#pragma unroll
      for (int i = 0; i < 4; ++i) { unsigned short hh, ll; split2(xr[p][i], hh, ll); Xhi[el + i] = hh; Xlo[el + i] = ll; }
    }
#pragma unroll
    for (int p = 0; p < 4; ++p) {
      const int r = srow + p * 16;
      const int el = r * 64 + (sk ^ ((r & 7) << 3));
#pragma unroll
      for (int i = 0; i < 4; ++i) { unsigned short hh, ll; split2(wr[p][i], hh, ll); Whi[el + i] = hh; Wlo[el + i] = ll; }
    }
    __syncthreads();

#pragma unroll
    for (int c = 0; c < 2; ++c) {
      const int koff = c * 32 + g * 8;
      s16x8 ah[4], al[4], bh[2], bl[2];
#pragma unroll
      for (int mi = 0; mi < 4; ++mi) {
        const int r = wm + mi * 16 + j;
        const int el = r * 64 + (koff ^ ((r & 7) << 3));
        ah[mi] = *reinterpret_cast<const s16x8*>(&Xhi[el]);
        al[mi] = *reinterpret_cast<const s16x8*>(&Xlo[el]);
      }
#pragma unroll
      for (int ni = 0; ni < 2; ++ni) {
        const int r = wn + ni * 16 + j;
        const int el = r * 64 + (koff ^ ((r & 7) << 3));
        bh[ni] = *reinterpret_cast<const s16x8*>(&Whi[el]);
        bl[ni] = *reinterpret_cast<const s16x8*>(&Wlo[el]);
      }
#pragma unroll
      for (int mi = 0; mi < 4; ++mi)
#pragma unroll
        for (int ni = 0; ni < 2; ++ni) {
          acc[mi][ni] = __builtin_amdgcn_mfma_f32_16x16x32_bf16(ah[mi], bh[ni], acc[mi][ni], 0, 0, 0);
          acc[mi][ni] = __builtin_amdgcn_mfma_f32_16x16x32_bf16(ah[mi], bl[ni], acc[mi][ni], 0, 0, 0);
          acc[mi][ni] = __builtin_amdgcn_mfma_f32_16x16x32_bf16(al[mi], bh[ni], acc[mi][ni], 0, 0, 0);
        }
    }
  }

#pragma unroll
  for (int ni = 0; ni < 2; ++ni) {
    const int colc = col0 + wn + ni * 16 + j;
    const float bj = bias[colc];
#pragma unroll
    for (int mi = 0; mi < 4; ++mi)
#pragma unroll
      for (int r = 0; r < 4; ++r) {
        const int rowc = row0 + wm + mi * 16 + (g << 2) + r;
        out[(size_t)rowc * FEAT + colc] = acc[mi][ni][r] + bj;
      }
  }
}

// ---------------------------------------------------------------------------
// Flash attention, swapped-operand 32x32x16 MFMA, direct-global K/V with
// register double-buffered prefetch (A/B sets, 2x-unrolled loop), no k-loop
// barriers. Block = 4 waves x 32 q-rows = 128 q. Grid 512 (XCD-swizzled).
// S^T = K*Q^T puts q at lane&31; cross-half exchange via __shfl_xor.
// ---------------------------------------------------------------------------
__global__ __launch_bounds__(256, 2) void attn_mfma32(
    const unsigned short* __restrict__ Qhi, const unsigned short* __restrict__ Qlo,
    const unsigned short* __restrict__ Khi, const unsigned short* __restrict__ Klo,
    const unsigned short* __restrict__ Vthi, const unsigned short* __restrict__ Vtlo,
    float* __restrict__ AO)
{
  __shared__ float bcast[4][32];

  const int tid = threadIdx.x, lane = tid & 63, wave = tid >> 6;
  const int hfl = lane >> 5;      // half of wave
  const int l31 = lane & 31;

  // XCD-chunked swizzle: 512 blocks = 8 XCDs x 64; each XCD gets 4 bh (4MB KV)
  const int bid = blockIdx.x;
  const int swz = (bid & 7) * 64 + (bid >> 3);
  const int qt  = swz & 15;
  const int bh  = swz >> 4;
  const int b = bh >> 3, h = bh & 7;

  const int q0 = qt * 128 + wave * 32;
  const size_t kvbase = (size_t)bh * SEQ * HD;

  // Q B-fragments (col=q=lane&31, k=hd=c*16+hfl*8+i), pre-scaled by 1/8
  s16x8 qh[4], ql[4];
  {
    const size_t qoff = kvbase + (size_t)(q0 + l31) * HD + hfl * 8;
#pragma unroll
    for (int c = 0; c < 4; ++c) {
      qh[c] = *reinterpret_cast<const s16x8*>(&Qhi[qoff + c * 16]);
      ql[c] = *reinterpret_cast<const s16x8*>(&Qlo[qoff + c * 16]);
    }
  }

  f32x16 oacc0 = (f32x16)0.f, oacc1 = (f32x16)0.f;
  float m = -INFINITY, l = 0.f;

  const unsigned short* kh_p = &Khi[kvbase + (size_t)l31 * HD + hfl * 8];
  const unsigned short* kl_p = &Klo[kvbase + (size_t)l31 * HD + hfl * 8];
  const size_t v0off = ((size_t)bh * HD + l31) * SEQ + hfl * 8;        // hd-tile 0
  const size_t v1off = ((size_t)bh * HD + 32 + l31) * SEQ + hfl * 8;   // hd-tile 1

  auto ldK = [&](int t, s16x8* KH, s16x8* KL) {
    const unsigned short* kh_t = kh_p + (size_t)t * HD;
    const unsigned short* kl_t = kl_p + (size_t)t * HD;
#pragma unroll
    for (int c = 0; c < 4; ++c) {
      KH[c] = *reinterpret_cast<const s16x8*>(&kh_t[c * 16]);
      KL[c] = *reinterpret_cast<const s16x8*>(&kl_t[c * 16]);
    }
  };
  auto ldV = [&](int t, s16x8* VH, s16x8* VL) {
    VH[0] = *reinterpret_cast<const s16x8*>(&Vthi[v0off + t]);
    VH[1] = *reinterpret_cast<const s16x8*>(&Vthi[v0off + t + 16]);
    VH[2] = *reinterpret_cast<const s16x8*>(&Vthi[v1off + t]);
    VH[3] = *reinterpret_cast<const s16x8*>(&Vthi[v1off + t + 16]);
    VL[0] = *reinterpret_cast<const s16x8*>(&Vtlo[v0off + t]);
    VL[1] = *reinterpret_cast<const s16x8*>(&Vtlo[v0off + t + 16]);
    VL[2] = *reinterpret_cast<const s16x8*>(&Vtlo[v1off + t]);
    VL[3] = *reinterpret_cast<const s16x8*>(&Vtlo[v1off + t + 16]);
  };

  auto tile = [&](const s16x8* KH, const s16x8* KL, const s16x8* VH, const s16x8* VL) {
    // ---- S^T = K Q^T ----
    f32x16 st = (f32x16)0.f;
    __builtin_amdgcn_s_setprio(1);
#pragma unroll
    for (int c = 0; c < 4; ++c) {
      st = __builtin_amdgcn_mfma_f32_32x32x16_bf16(KH[c], qh[c], st, 0, 0, 0);
      st = __builtin_amdgcn_mfma_f32_32x32x16_bf16(KH[c], ql[c], st, 0, 0, 0);
      st = __builtin_amdgcn_mfma_f32_32x32x16_bf16(KL[c], qh[c], st, 0, 0, 0);
    }
    __builtin_amdgcn_s_setprio(0);

    // ---- tile max over this lane's 16 keys + cross-half combine ----
    float pm = fmaxf(
        fmaxf(fmaxf(fmaxf(st[0], st[1]), fmaxf(st[2], st[3])),
              fmaxf(fmaxf(st[4], st[5]), fmaxf(st[6], st[7]))),
        fmaxf(fmaxf(fmaxf(st[8], st[9]), fmaxf(st[10], st[11])),
              fmaxf(fmaxf(st[12], st[13]), fmaxf(st[14], st[15]))));
    pm = fmaxf(pm, __shfl_xor(pm, 32));   // full 32-key row max, both halves

    // ---- defer-max rescale (rare; tile 0 always, corr=0 there) ----
    if (__any(pm > m + 8.f)) {
      const float mnew = fmaxf(m, pm);
      const float corr = __expf(m - mnew);
      m = mnew; l *= corr;
      if (lane < 32) bcast[wave][l31] = corr;
      f32x4 c4[4];
#pragma unroll
      for (int rq = 0; rq < 4; ++rq)
        c4[rq] = *reinterpret_cast<const f32x4*>(&bcast[wave][rq * 8 + hfl * 4]);
#pragma unroll
      for (int r = 0; r < 16; ++r) {
        const float cc = c4[r >> 2][r & 3];
        oacc0[r] *= cc; oacc1[r] *= cc;
      }
    }

    // ---- p = exp(s - m), row sum ----
    float rs = 0.f;
#pragma unroll
    for (int r = 0; r < 16; ++r) { st[r] = __expf(st[r] - m); rs += st[r]; }
    rs += __shfl_xor(rs, 32);
    l += rs;

    // ---- pack P hi/lo (proven split2), exchange halves via shfl_xor ----
    unsigned int wh[8], wl[8];
#pragma unroll
    for (int p = 0; p < 8; ++p) {
      unsigned short h0, l0, h1, l1;
      split2(st[2 * p], h0, l0);
      split2(st[2 * p + 1], h1, l1);
      wh[p] = (unsigned int)h0 | ((unsigned int)h1 << 16);
      wl[p] = (unsigned int)l0 | ((unsigned int)l1 << 16);
    }
    unsigned int sh[8], sl[8];
#pragma unroll
    for (int p = 0; p < 8; ++p) {
      sh[p] = (unsigned int)__shfl_xor((int)wh[p], 32);
      sl[p] = (unsigned int)__shfl_xor((int)wl[p], 32);
    }
    const bool lo = (hfl == 0);
    const unsigned int ah0 = lo ? wh[0] : sh[2];
    const unsigned int ah1 = lo ? wh[1] : sh[3];
    const unsigned int ah2 = lo ? sh[0] : wh[2];
    const unsigned int ah3 = lo ? sh[1] : wh[3];
    const unsigned int ah4 = lo ? wh[4] : sh[6];
    const unsigned int ah5 = lo ? wh[5] : sh[7];
    const unsigned int ah6 = lo ? sh[4] : wh[6];
    const unsigned int ah7 = lo ? sh[5] : wh[7];
    const unsigned int al0 = lo ? wl[0] : sl[2];
    const unsigned int al1 = lo ? wl[1] : sl[3];
    const unsigned int al2 = lo ? sl[0] : wl[2];
    const unsigned int al3 = lo ? sl[1] : wl[3];
    const unsigned int al4 = lo ? wl[4] : sl[6];
    const unsigned int al5 = lo ? wl[5] : sl[7];
    const unsigned int al6 = lo ? sl[4] : wl[6];
    const unsigned int al7 = lo ? sl[5] : wl[7];
    const s16x8 pa0h = __builtin_bit_cast(s16x8, (u32x4){ah0, ah1, ah2, ah3});
    const s16x8 pa1h = __builtin_bit_cast(s16x8, (u32x4){ah4, ah5, ah6, ah7});
    const s16x8 pa0l = __builtin_bit_cast(s16x8, (u32x4){al0, al1, al2, al3});
    const s16x8 pa1l = __builtin_bit_cast(s16x8, (u32x4){al4, al5, al6, al7});

    // ---- O += P V ----
    __builtin_amdgcn_s_setprio(1);
    oacc0 = __builtin_amdgcn_mfma_f32_32x32x16_bf16(pa0h, VH[0], oacc0, 0, 0, 0);
    oacc0 = __builtin_amdgcn_mfma_f32_32x32x16_bf16(pa0h, VL[0], oacc0, 0, 0, 0);
    oacc0 = __builtin_amdgcn_mfma_f32_32x32x16_bf16(pa0l, VH[0], oacc0, 0, 0, 0);
    oacc0 = __builtin_amdgcn_mfma_f32_32x32x16_bf16(pa1h, VH[1], oacc0, 0, 0, 0);
    oacc0 = __builtin_amdgcn_mfma_f32_32x32x16_bf16(pa1h, VL[1], oacc0, 0, 0, 0);
    oacc0 = __builtin_amdgcn_mfma_f32_32x32x16_bf16(pa1l, VH[1], oacc0, 0, 0, 0);
    oacc1 = __builtin_amdgcn_mfma_f32_32x32x16_bf16(pa0h, VH[2], oacc1, 0, 0, 0);
    oacc1 = __builtin_amdgcn_mfma_f32_32x32x16_bf16(pa0h, VL[2], oacc1, 0, 0, 0);
    oacc1 = __builtin_amdgcn_mfma_f32_32x32x16_bf16(pa0l, VH[2], oacc1, 0, 0, 0);
    oacc1 = __builtin_amdgcn_mfma_f32_32x32x16_bf16(pa1h, VH[3], oacc1, 0, 0, 0);
    oacc1 = __builtin_amdgcn_mfma_f32_32x32x16_bf16(pa1h, VL[3], oacc1, 0, 0, 0);
    oacc1 = __builtin_amdgcn_mfma_f32_32x32x16_bf16(pa1l, VH[3], oacc1, 0, 0, 0);
    __builtin_amdgcn_s_setprio(0);
  };

  // ---- main loop: A/B register double-buffer, prefetch one tile ahead ----
  s16x8 KHa[4], KLa[4], VHa[4], VLa[4];
  s16x8 KHb[4], KLb[4], VHb[4], VLb[4];
  ldK(0, KHa, KLa); ldV(0, VHa, VLa);
  for (int kt = 0; kt < SEQ; kt += 64) {
    ldK(kt + 32, KHb, KLb); ldV(kt + 32, VHb, VLb);
    tile(KHa, KLa, VHa, VLa);
    const int tn = (kt + 64) & (SEQ - 1);   // wrap on last iter (harmless)
    ldK(tn, KHa, KLa); ldV(tn, VHa, VLa);
    tile(KHb, KLb, VHb, VLb);
  }

  // ---- normalize (1/l broadcast via per-wave LDS) and store ----
  if (lane < 32) bcast[wave][l31] = 1.f / l;
  f32x4 i4[4];
#pragma unroll
  for (int rq = 0; rq < 4; ++rq)
    i4[rq] = *reinterpret_cast<const f32x4*>(&bcast[wave][rq * 8 + hfl * 4]);

#pragma unroll
  for (int r = 0; r < 16; ++r) {
    const int q = q0 + (r & 3) + 8 * (r >> 2) + 4 * hfl;
    const float inv = i4[r >> 2][r & 3];
    float* dst = &AO[((size_t)b * SEQ + q) * FEAT + h * HD + l31];
    dst[0]  = oacc0[r] * inv;
    dst[32] = oacc1[r] * inv;
  }
}

extern "C" void kernel_launch(void* const* d_in, const int* in_sizes, int n_in,
                              void* d_out, int out_size, void* d_ws, size_t ws_size,
                              hipStream_t stream) {
  const float* x_cur  = (const float*)d_in[0];
  const float* x_past = (const float*)d_in[1];
  const float* wq = (const float*)d_in[2];
  const float* bq = (const float*)d_in[3];
  const float* wk = (const float*)d_in[4];
  const float* bk = (const float*)d_in[5];
  const float* wv = (const float*)d_in[6];
  const float* bv = (const float*)d_in[7];
  const float* wo = (const float*)d_in[8];
  const float* bo = (const float*)d_in[9];
  float* out = (float*)d_out;

  const size_t n = (size_t)NROWS * FEAT;
  unsigned short* Qhi  = (unsigned short*)d_ws;
  unsigned short* Qlo  = Qhi + n;
  unsigned short* Khi  = Qhi + 2 * n;
  unsigned short* Klo  = Qhi + 3 * n;
  unsigned short* Vthi = Qhi + 4 * n;
  unsigned short* Vtlo = Qhi + 5 * n;
  float* AO = (float*)(Qhi + 6 * n);

  dim3 block(256);
  dim3 gqkv(NROWS / 128, FEAT / 64, 3);
  qkv_proj<<<gqkv, block, 0, stream>>>(x_cur, x_past, wq, bq, wk, bk, wv, bv,
                                       Qhi, Qlo, Khi, Klo, Vthi, Vtlo);

  attn_mfma32<<<dim3(512), block, 0, stream>>>(Qhi, Qlo, Khi, Klo, Vthi, Vtlo, AO);

  dim3 gout(NROWS / 128, FEAT / 64);
  out_proj<<<gout, block, 0, stream>>>(AO, wo, bo, out);
}